// Round 2
// baseline (3422.240 us; speedup 1.0000x reference)
//
#include <hip/hip_runtime.h>
#include <hip/hip_bf16.h>
#include <stdint.h>

// ContinuousEpisodicVLM: 3-step episodic retrieval loop.
// Heavy op: sims = patches[2048x768] @ memory[65536x768]^T + top-50 per patch.
// Strategy: bf16 MFMA candidate generation (sampled-threshold filter), exact
// f32 rescoring of candidates before selection/softmax so the committed patch
// state stays f32-exact (breaks the tau=0.02 error-amplification chain).

typedef __attribute__((ext_vector_type(8))) short short8;
typedef __attribute__((ext_vector_type(4))) float f32x4;

#define DIM    768
#define NPATCH 2048
#define NMEM   65536
#define NCLS   1000
#define NSAMP  4096   // sampled nodes (stride 16)
#define CAP    1024   // candidate buffer per patch
#define TAUINV 50.0f  // 1/0.02

__device__ __forceinline__ unsigned short f2bf(float f){
  unsigned b = __float_as_uint(f);
  b += 0x7FFFu + ((b >> 16) & 1u);      // RNE
  return (unsigned short)(b >> 16);
}
__device__ __forceinline__ unsigned encf(float x){
  unsigned b = __float_as_uint(x);
  return (b & 0x80000000u) ? ~b : (b | 0x80000000u);   // order-preserving uint key
}
__device__ __forceinline__ float decf(unsigned k){
  unsigned b = (k & 0x80000000u) ? (k & 0x7FFFFFFFu) : ~k;
  return __uint_as_float(b);
}

// ---------------- protos + anchors_bf16 ----------------
__global__ __launch_bounds__(256) void proto_kernel(
    const float* __restrict__ anchors, const float* __restrict__ sums,
    const float* __restrict__ counts, float* __restrict__ protos,
    unsigned short* __restrict__ anchors_bf)
{
  int c = blockIdx.x, t = threadIdx.x;
  if (c >= NCLS){  // pad rows 1000..1023 of anchors_bf with zeros
    for (int j = 0; j < 3; ++j) anchors_bf[(size_t)c*DIM + t + j*256] = 0;
    return;
  }
  __shared__ float wv[4]; __shared__ float bc;
  float cnt = fmaxf(counts[c], 1.0f);
  float v[3];
  #pragma unroll
  for (int j = 0; j < 3; ++j) v[j] = sums[(size_t)c*DIM + t + j*256] / cnt;
  float ss = v[0]*v[0] + v[1]*v[1] + v[2]*v[2];
  for (int off = 32; off > 0; off >>= 1) ss += __shfl_down(ss, off, 64);
  if ((t & 63) == 0) wv[t >> 6] = ss;
  __syncthreads();
  if (t == 0) bc = wv[0] + wv[1] + wv[2] + wv[3];
  __syncthreads();
  float rn = 1.0f / fmaxf(sqrtf(bc), 1e-12f);
  __syncthreads();
  float pr[3];
  #pragma unroll
  for (int j = 0; j < 3; ++j){
    float a = anchors[(size_t)c*DIM + t + j*256];
    pr[j] = a + v[j] * rn;                         // ALPHA = 1.0
    anchors_bf[(size_t)c*DIM + t + j*256] = f2bf(a);
  }
  ss = pr[0]*pr[0] + pr[1]*pr[1] + pr[2]*pr[2];
  for (int off = 32; off > 0; off >>= 1) ss += __shfl_down(ss, off, 64);
  if ((t & 63) == 0) wv[t >> 6] = ss;
  __syncthreads();
  if (t == 0) bc = wv[0] + wv[1] + wv[2] + wv[3];
  __syncthreads();
  float rn2 = 1.0f / fmaxf(sqrtf(bc), 1e-12f);
  #pragma unroll
  for (int j = 0; j < 3; ++j) protos[(size_t)c*DIM + t + j*256] = pr[j] * rn2;
}

// ---------------- patches f32+bf16 working copies ----------------
__global__ __launch_bounds__(256) void prep_patches(
    const float* __restrict__ tp, float* __restrict__ pc, unsigned short* __restrict__ pb)
{
  size_t i = (size_t)blockIdx.x*256 + threadIdx.x;   // float4 index
  float4 v = *(const float4*)(tp + i*4);
  *(float4*)(pc + i*4) = v;
  unsigned p0 = (unsigned)f2bf(v.x) | ((unsigned)f2bf(v.y) << 16);
  unsigned p1 = (unsigned)f2bf(v.z) | ((unsigned)f2bf(v.w) << 16);
  *(uint2*)(pb + i*4) = make_uint2(p0, p1);
}

// ---------------- zero counters / ev keys ----------------
__global__ void zero_kernel(int* __restrict__ counters, unsigned* __restrict__ ev_key,
                            const int* __restrict__ active)
{
  if (*active == 0) return;
  int i = blockIdx.x*256 + threadIdx.x;
  counters[i] = 0;
  ev_key[i]   = 0u;   // 0 < enc(x) for every real x
}

// ---------------- unified MFMA sims kernel ----------------
// MODE 0: full 65536 nodes, filter >= threshold, append candidate indices
// MODE 1: sampled 4096 nodes (stride 16), write sims_sample[patch][s]
// MODE 2: anchors (1024 rows, >=1000 invalid), atomicMax evidence per patch
// Tile: 64 A-rows resident in LDS (bf16, XOR-swizzled chunks), B = patches bf16
// [512 x 32k] per-k stage (XOR-swizzled). 8 waves, 4x4 16x16x32 acc per wave.
// LDS = 64*768*2 + 512*32*2 = 131072 B (128 KiB exactly).
template<int MODE>
__global__ __launch_bounds__(512, 2) void sims_kernel(
    const float* __restrict__ memf,
    const unsigned short* __restrict__ anchors_bf,
    const unsigned short* __restrict__ patches_bf,
    const float* __restrict__ thresholds,
    int* __restrict__ counters,
    int* __restrict__ cand_idx,
    float* __restrict__ sims_sample,
    unsigned* __restrict__ ev_key,
    const int* __restrict__ active)
{
  if (*active == 0) return;
  __shared__ __align__(16) unsigned short Al[64 * DIM];
  __shared__ __align__(16) unsigned short Bl[512 * 32];
  int t = threadIdx.x;
  int nb, pt0, pt1;
  if (MODE == 0)      { nb = blockIdx.x;        pt0 = 0;               pt1 = 4; }
  else if (MODE == 1) { nb = blockIdx.x & 63;   pt0 = blockIdx.x >> 6; pt1 = pt0 + 1; }
  else                { nb = blockIdx.x & 15;   pt0 = blockIdx.x >> 4; pt1 = pt0 + 1; }

  // --- stage A tile (64 rows x 768) as bf16, 16B chunks, slot = chunk ^ (row&7) ---
  if (MODE == 2){
    for (int i = t; i < 64*96; i += 512){
      int r = i / 96, c = i % 96;
      uint4 v = *(const uint4*)(anchors_bf + (size_t)(nb*64 + r)*DIM + c*8);
      int slot = c ^ (r & 7);
      *(uint4*)&Al[r*DIM + slot*8] = v;
    }
  } else {
    for (int i = t; i < 64*96; i += 512){
      int r = i / 96, c = i % 96;
      size_t row = (MODE == 1) ? (size_t)(nb*64 + r) * 16 : (size_t)(nb*64 + r);
      float4 va = *(const float4*)(memf + row*DIM + c*8);
      float4 vb = *(const float4*)(memf + row*DIM + c*8 + 4);
      uint4 u;
      u.x = (unsigned)f2bf(va.x) | ((unsigned)f2bf(va.y) << 16);
      u.y = (unsigned)f2bf(va.z) | ((unsigned)f2bf(va.w) << 16);
      u.z = (unsigned)f2bf(vb.x) | ((unsigned)f2bf(vb.y) << 16);
      u.w = (unsigned)f2bf(vb.z) | ((unsigned)f2bf(vb.w) << 16);
      int slot = c ^ (r & 7);
      *(uint4*)&Al[r*DIM + slot*8] = u;
    }
  }
  __syncthreads();

  int w = t >> 6, lane = t & 63, l15 = lane & 15, l4 = lane >> 4;

  for (int pt = pt0; pt < pt1; ++pt){
    int pbase = pt * 512;
    f32x4 acc[4][4];
    #pragma unroll
    for (int x = 0; x < 4; ++x)
      #pragma unroll
      for (int y = 0; y < 4; ++y) acc[x][y] = (f32x4){0.f, 0.f, 0.f, 0.f};

    for (int kk = 0; kk < 24; ++kk){
      __syncthreads();
      // stage B: [512 patches][32 k] bf16, 4x 16B chunks per row, slot = c ^ ((p>>1)&3)
      #pragma unroll
      for (int j = 0; j < 4; ++j){
        int id = t + j*512;
        int p = id >> 2, c = id & 3;
        uint4 v = *(const uint4*)(patches_bf + (size_t)(pbase + p)*DIM + kk*32 + c*8);
        int slot = c ^ ((p >> 1) & 3);
        *(uint4*)&Bl[p*32 + slot*8] = v;
      }
      __syncthreads();
      short8 af[4], bfr[4];
      #pragma unroll
      for (int ng = 0; ng < 4; ++ng){
        int row = ng*16 + l15;
        int chunk = kk*4 + l4;
        af[ng] = *(const short8*)&Al[row*DIM + (chunk ^ (row & 7))*8];
      }
      #pragma unroll
      for (int g = 0; g < 4; ++g){
        int p = w*64 + g*16 + l15;
        int slot = l4 ^ ((p >> 1) & 3);
        bfr[g] = *(const short8*)&Bl[p*32 + slot*8];
      }
      #pragma unroll
      for (int ng = 0; ng < 4; ++ng)
        #pragma unroll
        for (int g = 0; g < 4; ++g)
          acc[ng][g] = __builtin_amdgcn_mfma_f32_16x16x32_bf16(af[ng], bfr[g], acc[ng][g], 0, 0, 0);
    }

    // --- epilogue: C frag is col=lane&15 (patch), row=(lane>>4)*4+i (A row) ---
    if (MODE == 0){
      #pragma unroll
      for (int g = 0; g < 4; ++g){
        int patch = pbase + w*64 + g*16 + l15;
        float th = thresholds[patch];
        #pragma unroll
        for (int ng = 0; ng < 4; ++ng){
          #pragma unroll
          for (int i = 0; i < 4; ++i){
            float v = acc[ng][g][i];
            if (v >= th){
              int node = nb*64 + ng*16 + l4*4 + i;
              int pos = atomicAdd(&counters[patch], 1);
              if (pos < CAP) cand_idx[(size_t)patch*CAP + pos] = node;
            }
          }
        }
      }
    } else if (MODE == 1){
      #pragma unroll
      for (int g = 0; g < 4; ++g){
        int patch = pbase + w*64 + g*16 + l15;
        #pragma unroll
        for (int ng = 0; ng < 4; ++ng){
          int col = nb*64 + ng*16 + l4*4;
          *(f32x4*)(sims_sample + (size_t)patch*NSAMP + col) = acc[ng][g];
        }
      }
    } else {
      #pragma unroll
      for (int g = 0; g < 4; ++g){
        int patch = pbase + w*64 + g*16 + l15;
        float m = -3e38f; bool any = false;
        #pragma unroll
        for (int ng = 0; ng < 4; ++ng){
          #pragma unroll
          for (int i = 0; i < 4; ++i){
            int a = nb*64 + ng*16 + l4*4 + i;
            if (a < NCLS){ m = fmaxf(m, acc[ng][g][i]); any = true; }
          }
        }
        if (any) atomicMax(&ev_key[patch], encf(m));
      }
    }
  }
}

// ---------------- per-patch threshold = 16th max of 4096 sampled sims ----------------
__global__ __launch_bounds__(256) void thresh_kernel(
    const float* __restrict__ sims, float* __restrict__ thresholds, const int* __restrict__ active)
{
  if (*active == 0) return;
  __shared__ float s[NSAMP];
  __shared__ float wv[4]; __shared__ int wi[4];
  __shared__ float result;
  int p = blockIdx.x, t = threadIdx.x;
  const float4* src = (const float4*)(sims + (size_t)p*NSAMP);
  for (int i = t; i < NSAMP/4; i += 256) *(float4*)&s[i*4] = src[i];
  __syncthreads();
  for (int r = 0; r < 16; ++r){
    float v = -3e38f; int idx = 0;
    #pragma unroll
    for (int j = 0; j < 16; ++j){
      int ii = t*16 + j; float x = s[ii];
      if (x > v){ v = x; idx = ii; }
    }
    for (int off = 32; off > 0; off >>= 1){
      float ov = __shfl_down(v, off, 64); int oi = __shfl_down(idx, off, 64);
      if (ov > v || (ov == v && oi < idx)){ v = ov; idx = oi; }
    }
    if ((t & 63) == 0){ wv[t >> 6] = v; wi[t >> 6] = idx; }
    __syncthreads();
    if (t == 0){
      float bv = wv[0]; int bi = wi[0];
      for (int q = 1; q < 4; ++q)
        if (wv[q] > bv || (wv[q] == bv && wi[q] < bi)){ bv = wv[q]; bi = wi[q]; }
      s[bi] = -3e38f;
      if (r == 15) result = bv;
    }
    __syncthreads();
  }
  if (t == 0) thresholds[p] = result;
}

// ---------------- exact rescore -> top-50 -> softmax -> message -> renorm ----------------
__global__ __launch_bounds__(256) void msg_kernel(
    const int* __restrict__ counters, const int* __restrict__ cand_idx,
    const float* __restrict__ memf,
    float* __restrict__ pc, unsigned short* __restrict__ pb, const int* __restrict__ active)
{
  if (*active == 0) return;
  __shared__ float sc[CAP]; __shared__ int si[CAP];
  __shared__ __align__(16) float gl[DIM];
  __shared__ float selv[50]; __shared__ int seli[50]; __shared__ float attn[50];
  __shared__ float wv[4]; __shared__ int wi[4];
  __shared__ float bc;
  int p = blockIdx.x, t = threadIdx.x;
  int n = counters[p]; if (n > CAP) n = CAP;
  #pragma unroll
  for (int j = 0; j < 3; ++j) gl[t + j*256] = pc[(size_t)p*DIM + t + j*256];
  for (int i = t; i < CAP; i += 256){
    sc[i] = -3e38f;
    si[i] = (i < n) ? cand_idx[(size_t)p*CAP + i] : 0;
  }
  __syncthreads();
  // exact f32 rescore: one wave per candidate, 64 lanes x 12 dims
  int w = t >> 6, lane = t & 63;
  for (int i = w; i < n; i += 4){
    const float* row = memf + (size_t)si[i]*DIM;
    float s = 0.f;
    #pragma unroll
    for (int j = 0; j < 12; ++j){
      int d = lane + j*64;
      s += row[d] * gl[d];
    }
    for (int off = 32; off > 0; off >>= 1) s += __shfl_down(s, off, 64);
    if (lane == 0) sc[i] = s;
  }
  __syncthreads();
  int K = n < 50 ? n : 50;
  for (int r = 0; r < K; ++r){
    float v = -3e38f; int idx = 0;
    #pragma unroll
    for (int j = 0; j < 4; ++j){
      int ii = t*4 + j; float x = sc[ii];
      if (x > v){ v = x; idx = ii; }
    }
    for (int off = 32; off > 0; off >>= 1){
      float ov = __shfl_down(v, off, 64); int oi = __shfl_down(idx, off, 64);
      if (ov > v || (ov == v && oi < idx)){ v = ov; idx = oi; }
    }
    if ((t & 63) == 0){ wv[t >> 6] = v; wi[t >> 6] = idx; }
    __syncthreads();
    if (t == 0){
      float bv = wv[0]; int bi = wi[0];
      for (int q = 1; q < 4; ++q)
        if (wv[q] > bv || (wv[q] == bv && wi[q] < bi)){ bv = wv[q]; bi = wi[q]; }
      selv[r] = bv; seli[r] = si[bi]; sc[bi] = -3e38f;
    }
    __syncthreads();
  }
  if (t < K) attn[t] = __expf((selv[t] - selv[0]) * TAUINV);
  __syncthreads();
  if (t == 0){ float s = 0.f; for (int k = 0; k < K; ++k) s += attn[k]; bc = s; }
  __syncthreads();
  float inv = 1.0f / bc;
  int d0 = t, d1 = t + 256, d2 = t + 512;
  float a0 = gl[d0], a1 = gl[d1], a2 = gl[d2];
  for (int k = 0; k < K; ++k){
    float a = attn[k] * inv;
    const float* row = memf + (size_t)seli[k]*DIM;
    a0 += a * row[d0]; a1 += a * row[d1]; a2 += a * row[d2];
  }
  float ss = a0*a0 + a1*a1 + a2*a2;
  for (int off = 32; off > 0; off >>= 1) ss += __shfl_down(ss, off, 64);
  if ((t & 63) == 0) wv[t >> 6] = ss;
  __syncthreads();
  if (t == 0) bc = wv[0] + wv[1] + wv[2] + wv[3];
  __syncthreads();
  float rn = 1.0f / fmaxf(sqrtf(bc), 1e-12f);
  a0 *= rn; a1 *= rn; a2 *= rn;
  float* orow = pc + (size_t)p*DIM;
  orow[d0] = a0; orow[d1] = a1; orow[d2] = a2;
  unsigned short* brow = pb + (size_t)p*DIM;
  brow[d0] = f2bf(a0); brow[d1] = f2bf(a1); brow[d2] = f2bf(a2);
}

// ---------------- evidence softmax stats ----------------
__global__ __launch_bounds__(256) void pl1_kernel(
    const unsigned* __restrict__ ev_key, float* __restrict__ stats, const int* __restrict__ active)
{
  if (*active == 0) return;
  __shared__ float wv[4]; __shared__ float bc;
  int t = threadIdx.x;
  float m = -3e38f;
  for (int i = t; i < NPATCH; i += 256) m = fmaxf(m, decf(ev_key[i]));
  for (int off = 32; off > 0; off >>= 1) m = fmaxf(m, __shfl_down(m, off, 64));
  if ((t & 63) == 0) wv[t >> 6] = m;
  __syncthreads();
  if (t == 0) bc = fmaxf(fmaxf(wv[0], wv[1]), fmaxf(wv[2], wv[3]));
  __syncthreads();
  float M = bc;
  __syncthreads();
  float s = 0.f;
  for (int i = t; i < NPATCH; i += 256) s += __expf((decf(ev_key[i]) - M) * TAUINV);
  for (int off = 32; off > 0; off >>= 1) s += __shfl_down(s, off, 64);
  if ((t & 63) == 0) wv[t >> 6] = s;
  __syncthreads();
  if (t == 0){ stats[0] = M; stats[1] = wv[0] + wv[1] + wv[2] + wv[3]; }
}

// ---------------- weighted pooling partials (32 blocks x 64 patches) ----------------
__global__ __launch_bounds__(256) void pl2_kernel(
    const unsigned* __restrict__ ev_key, const float* __restrict__ stats,
    const float* __restrict__ pc, float* __restrict__ g_part, const int* __restrict__ active)
{
  if (*active == 0) return;
  int t = threadIdx.x, pbase = blockIdx.x * 64;
  float M = stats[0], invS = 1.0f / stats[1];
  float a0 = 0.f, a1 = 0.f, a2 = 0.f;
  for (int i = 0; i < 64; ++i){
    int p = pbase + i;
    float wgt = __expf((decf(ev_key[p]) - M) * TAUINV) * invS;
    const float* row = pc + (size_t)p*DIM;
    a0 += wgt * row[t]; a1 += wgt * row[t + 256]; a2 += wgt * row[t + 512];
  }
  g_part[blockIdx.x*DIM + t]       = a0;
  g_part[blockIdx.x*DIM + t + 256] = a1;
  g_part[blockIdx.x*DIM + t + 512] = a2;
}

// ---------------- reduce partials + normalize g ----------------
__global__ __launch_bounds__(256) void pl3_kernel(
    const float* __restrict__ g_part, float* __restrict__ g, const int* __restrict__ active)
{
  if (*active == 0) return;
  __shared__ float wv[4]; __shared__ float bc;
  int t = threadIdx.x;
  float gv[3]; float ss = 0.f;
  #pragma unroll
  for (int j = 0; j < 3; ++j){
    int d = t + j*256;
    float s = 0.f;
    for (int b = 0; b < 32; ++b) s += g_part[b*DIM + d];
    gv[j] = s; ss += s*s;
  }
  for (int off = 32; off > 0; off >>= 1) ss += __shfl_down(ss, off, 64);
  if ((t & 63) == 0) wv[t >> 6] = ss;
  __syncthreads();
  if (t == 0) bc = wv[0] + wv[1] + wv[2] + wv[3];
  __syncthreads();
  float rn = 1.0f / fmaxf(sqrtf(bc), 1e-12f);
  #pragma unroll
  for (int j = 0; j < 3; ++j) g[t + j*256] = gv[j] * rn;
}

// ---------------- logits + entropy + commit (INIT: sys1 from test_global) ----------------
template<bool INIT>
__global__ __launch_bounds__(256) void cm_kernel(
    const float* __restrict__ gsrc, const float* __restrict__ protos,
    float* __restrict__ logits_cur, int* __restrict__ step, int* __restrict__ active)
{
  if (!INIT && *active == 0) return;
  __shared__ __align__(16) float gl[DIM];
  __shared__ float lg[NCLS];
  __shared__ float wv[4]; __shared__ float bc;
  int t = threadIdx.x;
  #pragma unroll
  for (int j = 0; j < 3; ++j) gl[t + j*256] = gsrc[t + j*256];
  __syncthreads();
  for (int c = t; c < NCLS; c += 256){
    const float4* pr = (const float4*)(protos + (size_t)c*DIM);
    float s = 0.f;
    #pragma unroll 4
    for (int d4 = 0; d4 < DIM/4; ++d4){
      float4 pv = pr[d4];
      float4 gv = *(const float4*)&gl[d4*4];
      s += gv.x*pv.x + gv.y*pv.y + gv.z*pv.z + gv.w*pv.w;
    }
    float L = 100.0f * s;
    lg[c] = L; logits_cur[c] = L;
  }
  __syncthreads();
  // entropy of softmax(lg)
  float m = -3e38f;
  for (int c = t; c < NCLS; c += 256) m = fmaxf(m, lg[c]);
  for (int off = 32; off > 0; off >>= 1) m = fmaxf(m, __shfl_down(m, off, 64));
  if ((t & 63) == 0) wv[t >> 6] = m;
  __syncthreads();
  if (t == 0) bc = fmaxf(fmaxf(wv[0], wv[1]), fmaxf(wv[2], wv[3]));
  __syncthreads();
  float M = bc;
  __syncthreads();
  float s = 0.f;
  for (int c = t; c < NCLS; c += 256) s += __expf(lg[c] - M);
  for (int off = 32; off > 0; off >>= 1) s += __shfl_down(s, off, 64);
  if ((t & 63) == 0) wv[t >> 6] = s;
  __syncthreads();
  if (t == 0) bc = wv[0] + wv[1] + wv[2] + wv[3];
  __syncthreads();
  float S = bc;
  __syncthreads();
  float hp = 0.f;
  for (int c = t; c < NCLS; c += 256){
    float pcl = __expf(lg[c] - M) / S;
    hp += pcl * __logf(pcl + 1e-10f);
  }
  for (int off = 32; off > 0; off >>= 1) hp += __shfl_down(hp, off, 64);
  if ((t & 63) == 0) wv[t >> 6] = hp;
  __syncthreads();
  if (t == 0){
    float H = -(wv[0] + wv[1] + wv[2] + wv[3]);
    if (INIT){ *step = 0; *active = (H > 0.8f) ? 1 : 0; }
    else     { *step = *step + 1; *active = (H > 0.8f) ? 1 : 0; }
  }
}

// ---------------- publish ----------------
__global__ void pub_kernel(const float* __restrict__ logits_cur, const int* __restrict__ step,
                           float* __restrict__ out)
{
  int i = blockIdx.x*256 + threadIdx.x;
  if (i < NCLS) out[i] = logits_cur[i];
  else if (i == NCLS) out[i] = (float)(*step);
}

extern "C" void kernel_launch(void* const* d_in, const int* in_sizes, int n_in,
                              void* d_out, int out_size, void* d_ws, size_t ws_size,
                              hipStream_t stream)
{
  (void)in_sizes; (void)n_in; (void)out_size; (void)ws_size;
  const float* tg  = (const float*)d_in[0];   // [1,768]
  const float* tp  = (const float*)d_in[1];   // [2048,768]
  const float* mem = (const float*)d_in[2];   // [65536,768]
  const float* anc = (const float*)d_in[3];   // [1000,768]
  const float* cs  = (const float*)d_in[4];   // [1000,768]
  const float* cc  = (const float*)d_in[5];   // [1000]

  char* ws = (char*)d_ws;
  auto al = [](size_t x){ return (x + 255) & ~(size_t)255; };
  size_t OFF_PC   = 0;
  size_t OFF_PB   = al(OFF_PC   + (size_t)NPATCH*DIM*4);
  size_t OFF_PROT = al(OFF_PB   + (size_t)NPATCH*DIM*2);
  size_t OFF_ABF  = al(OFF_PROT + (size_t)NCLS*DIM*4);
  size_t OFF_SS   = al(OFF_ABF  + (size_t)1024*DIM*2);
  size_t OFF_THR  = al(OFF_SS   + (size_t)NPATCH*NSAMP*4);
  size_t OFF_CNT  = al(OFF_THR  + (size_t)NPATCH*4);
  size_t OFF_CI   = al(OFF_CNT  + (size_t)NPATCH*4);
  size_t OFF_EV   = al(OFF_CI   + (size_t)NPATCH*CAP*4);
  size_t OFF_STAT = al(OFF_EV   + (size_t)NPATCH*4);
  size_t OFF_GP   = al(OFF_STAT + 256);
  size_t OFF_G    = al(OFF_GP   + (size_t)32*DIM*4);
  size_t OFF_LC   = al(OFF_G    + (size_t)DIM*4);
  size_t OFF_STEP = al(OFF_LC   + (size_t)NCLS*4);
  // total ~56 MB

  float*          pc      = (float*)(ws + OFF_PC);
  unsigned short* pb      = (unsigned short*)(ws + OFF_PB);
  float*          protos  = (float*)(ws + OFF_PROT);
  unsigned short* abf     = (unsigned short*)(ws + OFF_ABF);
  float*          simss   = (float*)(ws + OFF_SS);
  float*          thr     = (float*)(ws + OFF_THR);
  int*            cnt     = (int*)(ws + OFF_CNT);
  int*            ci      = (int*)(ws + OFF_CI);
  unsigned*       evk     = (unsigned*)(ws + OFF_EV);
  float*          stats   = (float*)(ws + OFF_STAT);
  float*          gp      = (float*)(ws + OFF_GP);
  float*          g       = (float*)(ws + OFF_G);
  float*          lc      = (float*)(ws + OFF_LC);
  int*            stepp   = (int*)(ws + OFF_STEP);
  int*            activep = stepp + 1;

  proto_kernel<<<1024, 256, 0, stream>>>(anc, cs, cc, protos, abf);
  prep_patches<<<(NPATCH*DIM/4)/256, 256, 0, stream>>>(tp, pc, pb);
  cm_kernel<true><<<1, 256, 0, stream>>>(tg, protos, lc, stepp, activep);

  for (int it = 0; it < 3; ++it){
    zero_kernel<<<NPATCH/256, 256, 0, stream>>>(cnt, evk, activep);
    sims_kernel<1><<<256, 512, 0, stream>>>(mem, abf, pb, thr, cnt, ci, simss, evk, activep);
    thresh_kernel<<<NPATCH, 256, 0, stream>>>(simss, thr, activep);
    sims_kernel<0><<<NMEM/64, 512, 0, stream>>>(mem, abf, pb, thr, cnt, ci, simss, evk, activep);
    msg_kernel<<<NPATCH, 256, 0, stream>>>(cnt, ci, mem, pc, pb, activep);
    sims_kernel<2><<<64, 512, 0, stream>>>(mem, abf, pb, thr, cnt, ci, simss, evk, activep);
    pl1_kernel<<<1, 256, 0, stream>>>(evk, stats, activep);
    pl2_kernel<<<32, 256, 0, stream>>>(evk, stats, pc, gp, activep);
    pl3_kernel<<<1, 256, 0, stream>>>(gp, g, activep);
    cm_kernel<false><<<1, 256, 0, stream>>>(g, protos, lc, stepp, activep);
  }
  pub_kernel<<<4, 256, 0, stream>>>(lc, stepp, (float*)d_out);
}

// Round 3
// 2774.762 us; speedup vs baseline: 1.2333x; 1.2333x over previous
//
#include <hip/hip_runtime.h>
#include <hip/hip_bf16.h>
#include <stdint.h>

// ContinuousEpisodicVLM: 3-step episodic retrieval loop.
// Heavy op: sims = patches[2048x768] @ memory[65536x768]^T + top-50 per patch.
// bf16 MFMA candidate generation (sampled-threshold filter) + exact f32
// rescoring. GEMM = m97-style: BM=BN=128, BK=64, global_load_lds(16B) from
// pre-swizzled bf16 buffers, swizzled ds_read_b128, 3 blocks/CU.

typedef __attribute__((ext_vector_type(8))) short short8;
typedef __attribute__((ext_vector_type(4))) float f32x4;

#define DIM    768
#define NPATCH 2048
#define NMEM   65536
#define NCLS   1000
#define NSAMP  4096   // sampled nodes (stride 16)
#define CAP    1024   // candidate buffer per patch
#define TAUINV 50.0f  // 1/0.02

__device__ __forceinline__ unsigned short f2bf(float f){
  unsigned b = __float_as_uint(f);
  b += 0x7FFFu + ((b >> 16) & 1u);      // RNE
  return (unsigned short)(b >> 16);
}
__device__ __forceinline__ unsigned encf(float x){
  unsigned b = __float_as_uint(x);
  return (b & 0x80000000u) ? ~b : (b | 0x80000000u);
}
__device__ __forceinline__ float decf(unsigned k){
  unsigned b = (k & 0x80000000u) ? (k & 0x7FFFFFFFu) : ~k;
  return __uint_as_float(b);
}
__device__ __forceinline__ void gload16(const void* g, void* l){
  __builtin_amdgcn_global_load_lds(
      (const __attribute__((address_space(1))) unsigned int*)g,
      (__attribute__((address_space(3))) unsigned int*)l, 16, 0, 0);
}
__device__ __forceinline__ uint4 pack8(float4 a, float4 b){
  uint4 u;
  u.x = (unsigned)f2bf(a.x) | ((unsigned)f2bf(a.y) << 16);
  u.y = (unsigned)f2bf(a.z) | ((unsigned)f2bf(a.w) << 16);
  u.z = (unsigned)f2bf(b.x) | ((unsigned)f2bf(b.y) << 16);
  u.w = (unsigned)f2bf(b.z) | ((unsigned)f2bf(b.w) << 16);
  return u;
}

// ---------------- protos + anchors_bf16 (pre-swizzled) ----------------
__global__ __launch_bounds__(256) void proto_kernel(
    const float* __restrict__ anchors, const float* __restrict__ sums,
    const float* __restrict__ counts, float* __restrict__ protos,
    unsigned short* __restrict__ anchors_bf)
{
  int c = blockIdx.x, t = threadIdx.x;
  if (c >= NCLS){  // pad rows 1000..1023 with zeros
    for (int j = 0; j < 3; ++j) anchors_bf[(size_t)c*DIM + t + j*256] = 0;
    return;
  }
  __shared__ float wv[4]; __shared__ float bc;
  float cnt = fmaxf(counts[c], 1.0f);
  float v[3];
  #pragma unroll
  for (int j = 0; j < 3; ++j) v[j] = sums[(size_t)c*DIM + t + j*256] / cnt;
  float ss = v[0]*v[0] + v[1]*v[1] + v[2]*v[2];
  for (int off = 32; off > 0; off >>= 1) ss += __shfl_down(ss, off, 64);
  if ((t & 63) == 0) wv[t >> 6] = ss;
  __syncthreads();
  if (t == 0) bc = wv[0] + wv[1] + wv[2] + wv[3];
  __syncthreads();
  float rn = 1.0f / fmaxf(sqrtf(bc), 1e-12f);
  __syncthreads();
  float pr[3];
  #pragma unroll
  for (int j = 0; j < 3; ++j){
    int d = t + j*256;
    float a = anchors[(size_t)c*DIM + d];
    pr[j] = a + v[j] * rn;                         // ALPHA = 1.0
    // swizzled dest: chunk (d>>3) -> (d>>3)^(c&7) within its 128B block
    int dd = (d & ~63) | ((((d >> 3) ^ c) & 7) << 3) | (d & 7);
    anchors_bf[(size_t)c*DIM + dd] = f2bf(a);
  }
  ss = pr[0]*pr[0] + pr[1]*pr[1] + pr[2]*pr[2];
  for (int off = 32; off > 0; off >>= 1) ss += __shfl_down(ss, off, 64);
  if ((t & 63) == 0) wv[t >> 6] = ss;
  __syncthreads();
  if (t == 0) bc = wv[0] + wv[1] + wv[2] + wv[3];
  __syncthreads();
  float rn2 = 1.0f / fmaxf(sqrtf(bc), 1e-12f);
  #pragma unroll
  for (int j = 0; j < 3; ++j) protos[(size_t)c*DIM + t + j*256] = pr[j] * rn2;
}

// ---------------- patches f32 working copy ----------------
__global__ __launch_bounds__(256) void prep_patches(
    const float* __restrict__ tp, float* __restrict__ pc)
{
  size_t i = (size_t)blockIdx.x*256 + threadIdx.x;
  *(float4*)(pc + i*4) = *(const float4*)(tp + i*4);
}

// ---------------- f32 -> bf16 pre-swizzled conversion ----------------
// dst row r, 128B block b: chunk c8 stored at slot c8^(r&7).
__global__ __launch_bounds__(256) void conv_kernel(
    const float* __restrict__ src, unsigned short* __restrict__ dst, int rstride)
{
  int id = blockIdx.x*256 + threadIdx.x;   // one per 64-elem block
  int row = id / 12, blk = id % 12;
  const float4* s = (const float4*)(src + (size_t)row*rstride*DIM + blk*64);
  unsigned short* drow = dst + (size_t)row*DIM + blk*64;
  int key = row & 7;
  #pragma unroll
  for (int c8 = 0; c8 < 8; ++c8){
    uint4 u = pack8(s[c8*2], s[c8*2+1]);
    *(uint4*)(drow + (c8 ^ key)*8) = u;
  }
}

// ---------------- per-step K-major swizzled patch slab [12][2048][64] ----------------
__global__ __launch_bounds__(192) void slab_kernel(
    const float* __restrict__ pc, unsigned short* __restrict__ slab,
    const int* __restrict__ active)
{
  if (active && *active == 0) return;
  int b = blockIdx.x, t = threadIdx.x;      // grid 1024, 192 thr
  int p = b*2 + (t >= 96 ? 1 : 0);
  int q = (t >= 96) ? t - 96 : t;           // 0..95
  int ks = q >> 3, c8 = q & 7;
  const float* s = pc + (size_t)p*DIM + ks*64 + c8*8;
  uint4 u = pack8(*(const float4*)s, *(const float4*)(s + 4));
  *(uint4*)((char*)slab + (((size_t)ks*NPATCH + p)*128) + ((size_t)(c8 ^ (p & 7))*16)) = u;
}

// ---------------- zero counters / ev keys ----------------
__global__ void zero_kernel(int* __restrict__ counters, unsigned* __restrict__ ev_key,
                            const int* __restrict__ active)
{
  if (*active == 0) return;
  int i = blockIdx.x*256 + threadIdx.x;
  counters[i] = 0;
  ev_key[i]   = 0u;
}

// ---------------- unified MFMA GEMM ----------------
// MODE 0: A=mem_bf (512 node tiles), filter >= threshold, append candidates
// MODE 1: A=samp_bf (32 tiles), write sims_sample[patch][s]
// MODE 2: A=anchors_bf (8 tiles, rows>=1000 zero), atomicMax evidence
// 256 thr / 4 waves; BM=BN=128, BK=64; LDS 2x16KB; K = 12 steps.
template<int MODE>
__global__ __launch_bounds__(256, 3) void gemm_kernel(
    const unsigned short* __restrict__ Abf,
    const unsigned short* __restrict__ Bslab,
    const float* __restrict__ thresholds,
    int* __restrict__ counters,
    int* __restrict__ cand_idx,
    float* __restrict__ sims_sample,
    unsigned* __restrict__ ev_key,
    const int* __restrict__ active)
{
  if (*active == 0) return;
  __shared__ __align__(16) unsigned short Al[128*64];
  __shared__ __align__(16) unsigned short Bl[128*64];
  int b = blockIdx.x, nwg = gridDim.x;
  int wg = (b & 7)*(nwg >> 3) + (b >> 3);   // XCD-chunked swizzle (nwg%8==0)
  int mt = wg >> 4, pt = wg & 15;           // patch tile inner -> A-tile L2 share
  int t = threadIdx.x, w = t >> 6, lane = t & 63, l15 = lane & 15, l4 = lane >> 4;
  int wr = w >> 1, wc = w & 1;
  size_t arow0 = (size_t)mt*128;
  int pbase = pt*128;

  f32x4 acc[4][4];
  #pragma unroll
  for (int x = 0; x < 4; ++x)
    #pragma unroll
    for (int y = 0; y < 4; ++y) acc[x][y] = (f32x4){0.f, 0.f, 0.f, 0.f};

  const char* Ab = (const char*)Abf;
  const char* Bb = (const char*)Bslab;
  int srow = w*8 + (lane >> 3);             // + i*32 per issue
  int scol = (lane & 7)*16;

  for (int ks = 0; ks < 12; ++ks){
    if (ks) __syncthreads();
    #pragma unroll
    for (int i = 0; i < 4; ++i){
      const void* ga = Ab + ((arow0 + srow + i*32)*(size_t)(DIM*2)) + ks*128 + scol;
      gload16(ga, (char*)Al + i*4096 + w*1024);
      const void* gb = Bb + (((size_t)ks*NPATCH + pbase)*128) + i*4096 + w*1024 + lane*16;
      gload16(gb, (char*)Bl + i*4096 + w*1024);
    }
    __syncthreads();
    short8 af[2][4], bf_[2][4];
    #pragma unroll
    for (int kk = 0; kk < 2; ++kk){
      #pragma unroll
      for (int ng = 0; ng < 4; ++ng){
        int row = wr*64 + ng*16 + l15;
        int slot = (kk*4 + l4) ^ (row & 7);
        af[kk][ng] = *(const short8*)((const char*)Al + row*128 + slot*16);
      }
      #pragma unroll
      for (int g = 0; g < 4; ++g){
        int row = wc*64 + g*16 + l15;
        int slot = (kk*4 + l4) ^ (row & 7);
        bf_[kk][g] = *(const short8*)((const char*)Bl + row*128 + slot*16);
      }
    }
    #pragma unroll
    for (int kk = 0; kk < 2; ++kk)
      #pragma unroll
      for (int ng = 0; ng < 4; ++ng)
        #pragma unroll
        for (int g = 0; g < 4; ++g)
          acc[ng][g] = __builtin_amdgcn_mfma_f32_16x16x32_bf16(af[kk][ng], bf_[kk][g], acc[ng][g], 0, 0, 0);
  }

  // C frag: col(l15)=B row(patch), row(l4*4+i)=A row
  if (MODE == 0){
    #pragma unroll
    for (int g = 0; g < 4; ++g){
      int patch = pbase + wc*64 + g*16 + l15;
      float th = thresholds[patch];
      #pragma unroll
      for (int ng = 0; ng < 4; ++ng){
        #pragma unroll
        for (int i = 0; i < 4; ++i){
          float v = acc[ng][g][i];
          if (v >= th){
            int node = (int)arow0 + wr*64 + ng*16 + l4*4 + i;
            int pos = atomicAdd(&counters[patch], 1);
            if (pos < CAP) cand_idx[(size_t)patch*CAP + pos] = node;
          }
        }
      }
    }
  } else if (MODE == 1){
    #pragma unroll
    for (int g = 0; g < 4; ++g){
      int patch = pbase + wc*64 + g*16 + l15;
      #pragma unroll
      for (int ng = 0; ng < 4; ++ng){
        int col = (int)arow0 + wr*64 + ng*16 + l4*4;
        *(f32x4*)(sims_sample + (size_t)patch*NSAMP + col) = acc[ng][g];
      }
    }
  } else {
    #pragma unroll
    for (int g = 0; g < 4; ++g){
      int patch = pbase + wc*64 + g*16 + l15;
      float m = -3e38f; bool any = false;
      #pragma unroll
      for (int ng = 0; ng < 4; ++ng){
        #pragma unroll
        for (int i = 0; i < 4; ++i){
          int a = (int)arow0 + wr*64 + ng*16 + l4*4 + i;
          if (a < NCLS){ m = fmaxf(m, acc[ng][g][i]); any = true; }
        }
      }
      if (any) atomicMax(&ev_key[patch], encf(m));
    }
  }
}

// ---------------- per-patch threshold = 16th max of 4096 sampled sims ----------------
__global__ __launch_bounds__(256) void thresh_kernel(
    const float* __restrict__ sims, float* __restrict__ thresholds, const int* __restrict__ active)
{
  if (*active == 0) return;
  __shared__ float s[NSAMP];
  __shared__ float wv[4]; __shared__ int wi[4];
  __shared__ float result;
  int p = blockIdx.x, t = threadIdx.x;
  const float4* src = (const float4*)(sims + (size_t)p*NSAMP);
  for (int i = t; i < NSAMP/4; i += 256) *(float4*)&s[i*4] = src[i];
  __syncthreads();
  for (int r = 0; r < 16; ++r){
    float v = -3e38f; int idx = 0;
    #pragma unroll
    for (int j = 0; j < 16; ++j){
      int ii = t*16 + j; float x = s[ii];
      if (x > v){ v = x; idx = ii; }
    }
    for (int off = 32; off > 0; off >>= 1){
      float ov = __shfl_down(v, off, 64); int oi = __shfl_down(idx, off, 64);
      if (ov > v || (ov == v && oi < idx)){ v = ov; idx = oi; }
    }
    if ((t & 63) == 0){ wv[t >> 6] = v; wi[t >> 6] = idx; }
    __syncthreads();
    if (t == 0){
      float bv = wv[0]; int bi = wi[0];
      for (int q = 1; q < 4; ++q)
        if (wv[q] > bv || (wv[q] == bv && wi[q] < bi)){ bv = wv[q]; bi = wi[q]; }
      s[bi] = -3e38f;
      if (r == 15) result = bv;
    }
    __syncthreads();
  }
  if (t == 0) thresholds[p] = result;
}

// ---------------- exact rescore -> top-50 -> softmax -> message -> renorm ----------------
__global__ __launch_bounds__(256) void msg_kernel(
    const int* __restrict__ counters, const int* __restrict__ cand_idx,
    const float* __restrict__ memf,
    float* __restrict__ pc, const int* __restrict__ active)
{
  if (*active == 0) return;
  __shared__ float sc[CAP]; __shared__ int si[CAP];
  __shared__ __align__(16) float gl[DIM];
  __shared__ float selv[50]; __shared__ int seli[50]; __shared__ float attn[50];
  __shared__ float wv[4]; __shared__ int wi[4];
  __shared__ float bc;
  int p = blockIdx.x, t = threadIdx.x;
  int n = counters[p]; if (n > CAP) n = CAP;
  #pragma unroll
  for (int j = 0; j < 3; ++j) gl[t + j*256] = pc[(size_t)p*DIM + t + j*256];
  for (int i = t; i < CAP; i += 256){
    sc[i] = -3e38f;
    si[i] = (i < n) ? cand_idx[(size_t)p*CAP + i] : 0;
  }
  __syncthreads();
  int w = t >> 6, lane = t & 63;
  for (int i = w; i < n; i += 4){
    const float* row = memf + (size_t)si[i]*DIM;
    float s = 0.f;
    #pragma unroll
    for (int j = 0; j < 12; ++j){
      int d = lane + j*64;
      s += row[d] * gl[d];
    }
    for (int off = 32; off > 0; off >>= 1) s += __shfl_down(s, off, 64);
    if (lane == 0) sc[i] = s;
  }
  __syncthreads();
  int K = n < 50 ? n : 50;
  for (int r = 0; r < K; ++r){
    float v = -3e38f; int idx = 0;
    #pragma unroll
    for (int j = 0; j < 4; ++j){
      int ii = t*4 + j; float x = sc[ii];
      if (x > v){ v = x; idx = ii; }
    }
    for (int off = 32; off > 0; off >>= 1){
      float ov = __shfl_down(v, off, 64); int oi = __shfl_down(idx, off, 64);
      if (ov > v || (ov == v && oi < idx)){ v = ov; idx = oi; }
    }
    if ((t & 63) == 0){ wv[t >> 6] = v; wi[t >> 6] = idx; }
    __syncthreads();
    if (t == 0){
      float bv = wv[0]; int bi = wi[0];
      for (int q = 1; q < 4; ++q)
        if (wv[q] > bv || (wv[q] == bv && wi[q] < bi)){ bv = wv[q]; bi = wi[q]; }
      selv[r] = bv; seli[r] = si[bi]; sc[bi] = -3e38f;
    }
    __syncthreads();
  }
  if (t < K) attn[t] = __expf((selv[t] - selv[0]) * TAUINV);
  __syncthreads();
  if (t == 0){ float s = 0.f; for (int k = 0; k < K; ++k) s += attn[k]; bc = s; }
  __syncthreads();
  float inv = 1.0f / bc;
  int d0 = t, d1 = t + 256, d2 = t + 512;
  float a0 = gl[d0], a1 = gl[d1], a2 = gl[d2];
  for (int k = 0; k < K; ++k){
    float a = attn[k] * inv;
    const float* row = memf + (size_t)seli[k]*DIM;
    a0 += a * row[d0]; a1 += a * row[d1]; a2 += a * row[d2];
  }
  float ss = a0*a0 + a1*a1 + a2*a2;
  for (int off = 32; off > 0; off >>= 1) ss += __shfl_down(ss, off, 64);
  if ((t & 63) == 0) wv[t >> 6] = ss;
  __syncthreads();
  if (t == 0) bc = wv[0] + wv[1] + wv[2] + wv[3];
  __syncthreads();
  float rn = 1.0f / fmaxf(sqrtf(bc), 1e-12f);
  float* orow = pc + (size_t)p*DIM;
  orow[d0] = a0 * rn; orow[d1] = a1 * rn; orow[d2] = a2 * rn;
}

// ---------------- evidence softmax stats ----------------
__global__ __launch_bounds__(256) void pl1_kernel(
    const unsigned* __restrict__ ev_key, float* __restrict__ stats, const int* __restrict__ active)
{
  if (*active == 0) return;
  __shared__ float wv[4]; __shared__ float bc;
  int t = threadIdx.x;
  float m = -3e38f;
  for (int i = t; i < NPATCH; i += 256) m = fmaxf(m, decf(ev_key[i]));
  for (int off = 32; off > 0; off >>= 1) m = fmaxf(m, __shfl_down(m, off, 64));
  if ((t & 63) == 0) wv[t >> 6] = m;
  __syncthreads();
  if (t == 0) bc = fmaxf(fmaxf(wv[0], wv[1]), fmaxf(wv[2], wv[3]));
  __syncthreads();
  float M = bc;
  __syncthreads();
  float s = 0.f;
  for (int i = t; i < NPATCH; i += 256) s += __expf((decf(ev_key[i]) - M) * TAUINV);
  for (int off = 32; off > 0; off >>= 1) s += __shfl_down(s, off, 64);
  if ((t & 63) == 0) wv[t >> 6] = s;
  __syncthreads();
  if (t == 0){ stats[0] = M; stats[1] = wv[0] + wv[1] + wv[2] + wv[3]; }
}

// ---------------- weighted pooling partials ----------------
__global__ __launch_bounds__(256) void pl2_kernel(
    const unsigned* __restrict__ ev_key, const float* __restrict__ stats,
    const float* __restrict__ pc, float* __restrict__ g_part, const int* __restrict__ active)
{
  if (*active == 0) return;
  int t = threadIdx.x, pbase = blockIdx.x * 64;
  float M = stats[0], invS = 1.0f / stats[1];
  float a0 = 0.f, a1 = 0.f, a2 = 0.f;
  for (int i = 0; i < 64; ++i){
    int p = pbase + i;
    float wgt = __expf((decf(ev_key[p]) - M) * TAUINV) * invS;
    const float* row = pc + (size_t)p*DIM;
    a0 += wgt * row[t]; a1 += wgt * row[t + 256]; a2 += wgt * row[t + 512];
  }
  g_part[blockIdx.x*DIM + t]       = a0;
  g_part[blockIdx.x*DIM + t + 256] = a1;
  g_part[blockIdx.x*DIM + t + 512] = a2;
}

// ---------------- reduce partials + normalize g ----------------
__global__ __launch_bounds__(256) void pl3_kernel(
    const float* __restrict__ g_part, float* __restrict__ g, const int* __restrict__ active)
{
  if (*active == 0) return;
  __shared__ float wv[4]; __shared__ float bc;
  int t = threadIdx.x;
  float gv[3]; float ss = 0.f;
  #pragma unroll
  for (int j = 0; j < 3; ++j){
    int d = t + j*256;
    float s = 0.f;
    for (int b2 = 0; b2 < 32; ++b2) s += g_part[b2*DIM + d];
    gv[j] = s; ss += s*s;
  }
  for (int off = 32; off > 0; off >>= 1) ss += __shfl_down(ss, off, 64);
  if ((t & 63) == 0) wv[t >> 6] = ss;
  __syncthreads();
  if (t == 0) bc = wv[0] + wv[1] + wv[2] + wv[3];
  __syncthreads();
  float rn = 1.0f / fmaxf(sqrtf(bc), 1e-12f);
  #pragma unroll
  for (int j = 0; j < 3; ++j) g[t + j*256] = gv[j] * rn;
}

// ---------------- logits + entropy + commit ----------------
template<bool INIT>
__global__ __launch_bounds__(256) void cm_kernel(
    const float* __restrict__ gsrc, const float* __restrict__ protos,
    float* __restrict__ logits_cur, int* __restrict__ step, int* __restrict__ active)
{
  if (!INIT && *active == 0) return;
  __shared__ __align__(16) float gl[DIM];
  __shared__ float lg[NCLS];
  __shared__ float wv[4]; __shared__ float bc;
  int t = threadIdx.x;
  #pragma unroll
  for (int j = 0; j < 3; ++j) gl[t + j*256] = gsrc[t + j*256];
  __syncthreads();
  for (int c = t; c < NCLS; c += 256){
    const float4* pr = (const float4*)(protos + (size_t)c*DIM);
    float s = 0.f;
    #pragma unroll 4
    for (int d4 = 0; d4 < DIM/4; ++d4){
      float4 pv = pr[d4];
      float4 gv = *(const float4*)&gl[d4*4];
      s += gv.x*pv.x + gv.y*pv.y + gv.z*pv.z + gv.w*pv.w;
    }
    float L = 100.0f * s;
    lg[c] = L; logits_cur[c] = L;
  }
  __syncthreads();
  float m = -3e38f;
  for (int c = t; c < NCLS; c += 256) m = fmaxf(m, lg[c]);
  for (int off = 32; off > 0; off >>= 1) m = fmaxf(m, __shfl_down(m, off, 64));
  if ((t & 63) == 0) wv[t >> 6] = m;
  __syncthreads();
  if (t == 0) bc = fmaxf(fmaxf(wv[0], wv[1]), fmaxf(wv[2], wv[3]));
  __syncthreads();
  float M = bc;
  __syncthreads();
  float s = 0.f;
  for (int c = t; c < NCLS; c += 256) s += __expf(lg[c] - M);
  for (int off = 32; off > 0; off >>= 1) s += __shfl_down(s, off, 64);
  if ((t & 63) == 0) wv[t >> 6] = s;
  __syncthreads();
  if (t == 0) bc = wv[0] + wv[1] + wv[2] + wv[3];
  __syncthreads();
  float S = bc;
  __syncthreads();
  float hp = 0.f;
  for (int c = t; c < NCLS; c += 256){
    float pcl = __expf(lg[c] - M) / S;
    hp += pcl * __logf(pcl + 1e-10f);
  }
  for (int off = 32; off > 0; off >>= 1) hp += __shfl_down(hp, off, 64);
  if ((t & 63) == 0) wv[t >> 6] = hp;
  __syncthreads();
  if (t == 0){
    float H = -(wv[0] + wv[1] + wv[2] + wv[3]);
    if (INIT){ *step = 0; *active = (H > 0.8f) ? 1 : 0; }
    else     { *step = *step + 1; *active = (H > 0.8f) ? 1 : 0; }
  }
}

// ---------------- publish ----------------
__global__ void pub_kernel(const float* __restrict__ logits_cur, const int* __restrict__ step,
                           float* __restrict__ out)
{
  int i = blockIdx.x*256 + threadIdx.x;
  if (i < NCLS) out[i] = logits_cur[i];
  else if (i == NCLS) out[i] = (float)(*step);
}

extern "C" void kernel_launch(void* const* d_in, const int* in_sizes, int n_in,
                              void* d_out, int out_size, void* d_ws, size_t ws_size,
                              hipStream_t stream)
{
  (void)in_sizes; (void)n_in; (void)out_size; (void)ws_size;
  const float* tg  = (const float*)d_in[0];   // [1,768]
  const float* tp  = (const float*)d_in[1];   // [2048,768]
  const float* mem = (const float*)d_in[2];   // [65536,768]
  const float* anc = (const float*)d_in[3];   // [1000,768]
  const float* cs  = (const float*)d_in[4];   // [1000,768]
  const float* cc  = (const float*)d_in[5];   // [1000]

  char* ws = (char*)d_ws;
  auto al = [](size_t x){ return (x + 255) & ~(size_t)255; };
  size_t OFF_PC   = 0;
  size_t OFF_PROT = al(OFF_PC   + (size_t)NPATCH*DIM*4);
  size_t OFF_ABF  = al(OFF_PROT + (size_t)NCLS*DIM*4);
  size_t OFF_MBF  = al(OFF_ABF  + (size_t)1024*DIM*2);
  size_t OFF_SBF  = al(OFF_MBF  + (size_t)NMEM*DIM*2);
  size_t OFF_SLAB = al(OFF_SBF  + (size_t)NSAMP*DIM*2);
  size_t OFF_SS   = al(OFF_SLAB + (size_t)NPATCH*DIM*2);
  size_t OFF_THR  = al(OFF_SS   + (size_t)NPATCH*NSAMP*4);
  size_t OFF_CNT  = al(OFF_THR  + (size_t)NPATCH*4);
  size_t OFF_CI   = al(OFF_CNT  + (size_t)NPATCH*4);
  size_t OFF_EV   = al(OFF_CI   + (size_t)NPATCH*CAP*4);
  size_t OFF_STAT = al(OFF_EV   + (size_t)NPATCH*4);
  size_t OFF_GP   = al(OFF_STAT + 256);
  size_t OFF_G    = al(OFF_GP   + (size_t)32*DIM*4);
  size_t OFF_LC   = al(OFF_G    + (size_t)DIM*4);
  size_t OFF_STEP = al(OFF_LC   + (size_t)NCLS*4);
  // total ~165 MB

  float*          pc      = (float*)(ws + OFF_PC);
  float*          protos  = (float*)(ws + OFF_PROT);
  unsigned short* abf     = (unsigned short*)(ws + OFF_ABF);
  unsigned short* mbf     = (unsigned short*)(ws + OFF_MBF);
  unsigned short* sbf     = (unsigned short*)(ws + OFF_SBF);
  unsigned short* slab    = (unsigned short*)(ws + OFF_SLAB);
  float*          simss   = (float*)(ws + OFF_SS);
  float*          thr     = (float*)(ws + OFF_THR);
  int*            cnt     = (int*)(ws + OFF_CNT);
  int*            ci      = (int*)(ws + OFF_CI);
  unsigned*       evk     = (unsigned*)(ws + OFF_EV);
  float*          stats   = (float*)(ws + OFF_STAT);
  float*          gp      = (float*)(ws + OFF_GP);
  float*          g       = (float*)(ws + OFF_G);
  float*          lc      = (float*)(ws + OFF_LC);
  int*            stepp   = (int*)(ws + OFF_STEP);
  int*            activep = stepp + 1;

  proto_kernel<<<1024, 256, 0, stream>>>(anc, cs, cc, protos, abf);
  prep_patches<<<(NPATCH*DIM/4)/256, 256, 0, stream>>>(tp, pc);
  conv_kernel<<<(NMEM*12)/256, 256, 0, stream>>>(mem, mbf, 1);
  conv_kernel<<<(NSAMP*12)/256, 256, 0, stream>>>(mem, sbf, 16);
  cm_kernel<true><<<1, 256, 0, stream>>>(tg, protos, lc, stepp, activep);
  slab_kernel<<<NPATCH/2, 192, 0, stream>>>(pc, slab, nullptr);

  for (int it = 0; it < 3; ++it){
    zero_kernel<<<NPATCH/256, 256, 0, stream>>>(cnt, evk, activep);
    gemm_kernel<1><<<(NSAMP/128)*16, 256, 0, stream>>>(sbf, slab, thr, cnt, ci, simss, evk, activep);
    thresh_kernel<<<NPATCH, 256, 0, stream>>>(simss, thr, activep);
    gemm_kernel<0><<<(NMEM/128)*16, 256, 0, stream>>>(mbf, slab, thr, cnt, ci, simss, evk, activep);
    msg_kernel<<<NPATCH, 256, 0, stream>>>(cnt, ci, mem, pc, activep);
    slab_kernel<<<NPATCH/2, 192, 0, stream>>>(pc, slab, activep);
    gemm_kernel<2><<<(1024/128)*16, 256, 0, stream>>>(abf, slab, thr, cnt, ci, simss, evk, activep);
    pl1_kernel<<<1, 256, 0, stream>>>(evk, stats, activep);
    pl2_kernel<<<32, 256, 0, stream>>>(evk, stats, pc, gp, activep);
    pl3_kernel<<<1, 256, 0, stream>>>(gp, g, activep);
    cm_kernel<false><<<1, 256, 0, stream>>>(g, protos, lc, stepp, activep);
  }
  pub_kernel<<<4, 256, 0, stream>>>(lc, stepp, (float*)d_out);
}

// Round 4
// 2387.880 us; speedup vs baseline: 1.4332x; 1.1620x over previous
//
#include <hip/hip_runtime.h>
#include <hip/hip_bf16.h>
#include <stdint.h>

// ContinuousEpisodicVLM: 3-step episodic retrieval loop.
// bf16 MFMA candidate generation (sampled-threshold filter) + bf16-top-64
// preselect + exact f32 rescore of 64 + exact top-50 softmax message.

typedef __attribute__((ext_vector_type(8))) short short8;
typedef __attribute__((ext_vector_type(4))) float f32x4;

#define DIM    768
#define NPATCH 2048
#define NMEM   65536
#define NCLS   1000
#define NSAMP  4096   // sample = first 4096 rows
#define CAP    1024   // candidate buffer per patch
#define PRESEL 64     // bf16-score preselection width
#define TAUINV 50.0f  // 1/0.02

__device__ __forceinline__ unsigned short f2bf(float f){
  unsigned b = __float_as_uint(f);
  b += 0x7FFFu + ((b >> 16) & 1u);      // RNE
  return (unsigned short)(b >> 16);
}
__device__ __forceinline__ unsigned encf(float x){
  unsigned b = __float_as_uint(x);
  return (b & 0x80000000u) ? ~b : (b | 0x80000000u);
}
__device__ __forceinline__ float decf(unsigned k){
  unsigned b = (k & 0x80000000u) ? (k & 0x7FFFFFFFu) : ~k;
  return __uint_as_float(b);
}
__device__ __forceinline__ void gload16(const void* g, void* l){
  __builtin_amdgcn_global_load_lds(
      (const __attribute__((address_space(1))) unsigned int*)g,
      (__attribute__((address_space(3))) unsigned int*)l, 16, 0, 0);
}
__device__ __forceinline__ uint4 pack8(float4 a, float4 b){
  uint4 u;
  u.x = (unsigned)f2bf(a.x) | ((unsigned)f2bf(a.y) << 16);
  u.y = (unsigned)f2bf(a.z) | ((unsigned)f2bf(a.w) << 16);
  u.z = (unsigned)f2bf(b.x) | ((unsigned)f2bf(b.y) << 16);
  u.w = (unsigned)f2bf(b.z) | ((unsigned)f2bf(b.w) << 16);
  return u;
}

// ---------------- protos + anchors_bf16 (pre-swizzled) ----------------
__global__ __launch_bounds__(256) void proto_kernel(
    const float* __restrict__ anchors, const float* __restrict__ sums,
    const float* __restrict__ counts, float* __restrict__ protos,
    unsigned short* __restrict__ anchors_bf)
{
  int c = blockIdx.x, t = threadIdx.x;
  if (c >= NCLS){  // pad rows 1000..1023 with zeros
    for (int j = 0; j < 3; ++j) anchors_bf[(size_t)c*DIM + t + j*256] = 0;
    return;
  }
  __shared__ float wv[4]; __shared__ float bc;
  float cnt = fmaxf(counts[c], 1.0f);
  float v[3];
  #pragma unroll
  for (int j = 0; j < 3; ++j) v[j] = sums[(size_t)c*DIM + t + j*256] / cnt;
  float ss = v[0]*v[0] + v[1]*v[1] + v[2]*v[2];
  for (int off = 32; off > 0; off >>= 1) ss += __shfl_down(ss, off, 64);
  if ((t & 63) == 0) wv[t >> 6] = ss;
  __syncthreads();
  if (t == 0) bc = wv[0] + wv[1] + wv[2] + wv[3];
  __syncthreads();
  float rn = 1.0f / fmaxf(sqrtf(bc), 1e-12f);
  __syncthreads();
  float pr[3];
  #pragma unroll
  for (int j = 0; j < 3; ++j){
    int d = t + j*256;
    float a = anchors[(size_t)c*DIM + d];
    pr[j] = a + v[j] * rn;                         // ALPHA = 1.0
    int dd = (d & ~63) | ((((d >> 3) ^ c) & 7) << 3) | (d & 7);
    anchors_bf[(size_t)c*DIM + dd] = f2bf(a);
  }
  ss = pr[0]*pr[0] + pr[1]*pr[1] + pr[2]*pr[2];
  for (int off = 32; off > 0; off >>= 1) ss += __shfl_down(ss, off, 64);
  if ((t & 63) == 0) wv[t >> 6] = ss;
  __syncthreads();
  if (t == 0) bc = wv[0] + wv[1] + wv[2] + wv[3];
  __syncthreads();
  float rn2 = 1.0f / fmaxf(sqrtf(bc), 1e-12f);
  #pragma unroll
  for (int j = 0; j < 3; ++j) protos[(size_t)c*DIM + t + j*256] = pr[j] * rn2;
}

// ---------------- patches f32 working copy ----------------
__global__ __launch_bounds__(256) void prep_patches(
    const float* __restrict__ tp, float* __restrict__ pc)
{
  size_t i = (size_t)blockIdx.x*256 + threadIdx.x;
  *(float4*)(pc + i*4) = *(const float4*)(tp + i*4);
}

// ---------------- f32 -> bf16 pre-swizzled conversion ----------------
__global__ __launch_bounds__(256) void conv_kernel(
    const float* __restrict__ src, unsigned short* __restrict__ dst)
{
  int id = blockIdx.x*256 + threadIdx.x;   // one per 64-elem block
  int row = id / 12, blk = id % 12;
  const float4* s = (const float4*)(src + (size_t)row*DIM + blk*64);
  unsigned short* drow = dst + (size_t)row*DIM + blk*64;
  int key = row & 7;
  #pragma unroll
  for (int c8 = 0; c8 < 8; ++c8){
    uint4 u = pack8(s[c8*2], s[c8*2+1]);
    *(uint4*)(drow + (c8 ^ key)*8) = u;
  }
}

// ---------------- per-step K-major swizzled patch slab [12][2048][64] ----------------
__global__ __launch_bounds__(192) void slab_kernel(
    const float* __restrict__ pc, unsigned short* __restrict__ slab,
    const int* __restrict__ active)
{
  if (active && *active == 0) return;
  int b = blockIdx.x, t = threadIdx.x;
  int p = b*2 + (t >= 96 ? 1 : 0);
  int q = (t >= 96) ? t - 96 : t;
  int ks = q >> 3, c8 = q & 7;
  const float* s = pc + (size_t)p*DIM + ks*64 + c8*8;
  uint4 u = pack8(*(const float4*)s, *(const float4*)(s + 4));
  *(uint4*)((char*)slab + (((size_t)ks*NPATCH + p)*128) + ((size_t)(c8 ^ (p & 7))*16)) = u;
}

// ---------------- zero counters / ev keys ----------------
__global__ void zero_kernel(int* __restrict__ counters, unsigned* __restrict__ ev_key,
                            const int* __restrict__ active)
{
  if (*active == 0) return;
  int i = blockIdx.x*256 + threadIdx.x;
  counters[i] = 0;
  ev_key[i]   = 0u;
}

// ---------------- unified MFMA GEMM ----------------
// MODE 0: A=mbf rows rowbase.., filter >= threshold, append idx+score
// MODE 1: A=mbf rows 0..4095, write sims_sample[patch][node]
// MODE 2: A=anchors_bf (rows>=1000 zero), atomicMax evidence
template<int MODE>
__global__ __launch_bounds__(256, 3) void gemm_kernel(
    const unsigned short* __restrict__ Abf, int rowbase,
    const unsigned short* __restrict__ Bslab,
    const float* __restrict__ thresholds,
    int* __restrict__ counters,
    int* __restrict__ cand_idx,
    float* __restrict__ cand_score,
    float* __restrict__ sims_sample,
    unsigned* __restrict__ ev_key,
    const int* __restrict__ active)
{
  if (*active == 0) return;
  __shared__ __align__(16) unsigned short Al[128*64];
  __shared__ __align__(16) unsigned short Bl[128*64];
  int b = blockIdx.x, nwg = gridDim.x;
  int wg = (b & 7)*(nwg >> 3) + (b >> 3);   // XCD-chunked swizzle (nwg%8==0)
  int mt = wg >> 4, pt = wg & 15;
  int t = threadIdx.x, w = t >> 6, lane = t & 63, l15 = lane & 15, l4 = lane >> 4;
  int wr = w >> 1, wc = w & 1;
  size_t arow0 = (size_t)rowbase + (size_t)mt*128;
  int pbase = pt*128;

  f32x4 acc[4][4];
  #pragma unroll
  for (int x = 0; x < 4; ++x)
    #pragma unroll
    for (int y = 0; y < 4; ++y) acc[x][y] = (f32x4){0.f, 0.f, 0.f, 0.f};

  const char* Ab = (const char*)Abf;
  const char* Bb = (const char*)Bslab;
  int srow = w*8 + (lane >> 3);
  int scol = (lane & 7)*16;

  for (int ks = 0; ks < 12; ++ks){
    if (ks) __syncthreads();
    #pragma unroll
    for (int i = 0; i < 4; ++i){
      const void* ga = Ab + ((arow0 + srow + i*32)*(size_t)(DIM*2)) + ks*128 + scol;
      gload16(ga, (char*)Al + i*4096 + w*1024);
      const void* gb = Bb + (((size_t)ks*NPATCH + pbase)*128) + i*4096 + w*1024 + lane*16;
      gload16(gb, (char*)Bl + i*4096 + w*1024);
    }
    __syncthreads();
    short8 af[2][4], bf_[2][4];
    #pragma unroll
    for (int kk = 0; kk < 2; ++kk){
      #pragma unroll
      for (int ng = 0; ng < 4; ++ng){
        int row = wr*64 + ng*16 + l15;
        int slot = (kk*4 + l4) ^ (row & 7);
        af[kk][ng] = *(const short8*)((const char*)Al + row*128 + slot*16);
      }
      #pragma unroll
      for (int g = 0; g < 4; ++g){
        int row = wc*64 + g*16 + l15;
        int slot = (kk*4 + l4) ^ (row & 7);
        bf_[kk][g] = *(const short8*)((const char*)Bl + row*128 + slot*16);
      }
    }
    #pragma unroll
    for (int kk = 0; kk < 2; ++kk)
      #pragma unroll
      for (int ng = 0; ng < 4; ++ng)
        #pragma unroll
        for (int g = 0; g < 4; ++g)
          acc[ng][g] = __builtin_amdgcn_mfma_f32_16x16x32_bf16(af[kk][ng], bf_[kk][g], acc[ng][g], 0, 0, 0);
  }

  if (MODE == 0){
    #pragma unroll
    for (int g = 0; g < 4; ++g){
      int patch = pbase + wc*64 + g*16 + l15;
      float th = thresholds[patch];
      #pragma unroll
      for (int ng = 0; ng < 4; ++ng){
        #pragma unroll
        for (int i = 0; i < 4; ++i){
          float v = acc[ng][g][i];
          if (v >= th){
            int node = (int)arow0 + wr*64 + ng*16 + l4*4 + i;
            int pos = atomicAdd(&counters[patch], 1);
            if (pos < CAP){
              cand_idx[(size_t)patch*CAP + pos]   = node;
              cand_score[(size_t)patch*CAP + pos] = v;
            }
          }
        }
      }
    }
  } else if (MODE == 1){
    #pragma unroll
    for (int g = 0; g < 4; ++g){
      int patch = pbase + wc*64 + g*16 + l15;
      #pragma unroll
      for (int ng = 0; ng < 4; ++ng){
        int col = (int)arow0 + wr*64 + ng*16 + l4*4;
        *(f32x4*)(sims_sample + (size_t)patch*NSAMP + col) = acc[ng][g];
      }
    }
  } else {
    #pragma unroll
    for (int g = 0; g < 4; ++g){
      int patch = pbase + wc*64 + g*16 + l15;
      float m = -3e38f; bool any = false;
      #pragma unroll
      for (int ng = 0; ng < 4; ++ng){
        #pragma unroll
        for (int i = 0; i < 4; ++i){
          int a = (int)arow0 + wr*64 + ng*16 + l4*4 + i;
          if (a < NCLS){ m = fmaxf(m, acc[ng][g][i]); any = true; }
        }
      }
      if (any) atomicMax(&ev_key[patch], encf(m));
    }
  }
}

// -------- threshold = 16th max of 4096 sampled sims; append sampled cands --------
__global__ __launch_bounds__(256) void thresh_kernel(
    const float* __restrict__ sims, float* __restrict__ thresholds,
    int* __restrict__ counters, int* __restrict__ cand_idx,
    float* __restrict__ cand_score, const int* __restrict__ active)
{
  if (*active == 0) return;
  __shared__ float s[NSAMP];
  __shared__ float wv[4]; __shared__ int wi[4];
  __shared__ float tv16[16]; __shared__ int ti16[16];
  __shared__ float result;
  int p = blockIdx.x, t = threadIdx.x;
  const float4* src = (const float4*)(sims + (size_t)p*NSAMP);
  for (int i = t; i < NSAMP/4; i += 256) *(float4*)&s[i*4] = src[i];
  __syncthreads();
  for (int r = 0; r < 16; ++r){
    float v = -3e38f; int idx = 0;
    #pragma unroll
    for (int j = 0; j < 16; ++j){
      int ii = t*16 + j; float x = s[ii];
      if (x > v){ v = x; idx = ii; }
    }
    for (int off = 32; off > 0; off >>= 1){
      float ov = __shfl_down(v, off, 64); int oi = __shfl_down(idx, off, 64);
      if (ov > v || (ov == v && oi < idx)){ v = ov; idx = oi; }
    }
    if ((t & 63) == 0){ wv[t >> 6] = v; wi[t >> 6] = idx; }
    __syncthreads();
    if (t == 0){
      float bv = wv[0]; int bi = wi[0];
      for (int q = 1; q < 4; ++q)
        if (wv[q] > bv || (wv[q] == bv && wi[q] < bi)){ bv = wv[q]; bi = wi[q]; }
      s[bi] = -3e38f;
      tv16[r] = bv; ti16[r] = bi;
      if (r == 15) result = bv;
    }
    __syncthreads();
  }
  float th = result;
  if (t == 0){
    thresholds[p] = th;
    int pos = atomicAdd(&counters[p], 16);          // pos = 0
    #pragma unroll
    for (int k = 0; k < 16; ++k){
      cand_idx[(size_t)p*CAP + pos + k]   = ti16[k];
      cand_score[(size_t)p*CAP + pos + k] = tv16[k];
    }
  }
  __syncthreads();
  // ties: remaining sampled values >= th (top-16 already destroyed)
  for (int i = t; i < NSAMP; i += 256){
    float x = s[i];
    if (x >= th){
      int pos = atomicAdd(&counters[p], 1);
      if (pos < CAP){
        cand_idx[(size_t)p*CAP + pos]   = i;
        cand_score[(size_t)p*CAP + pos] = x;
      }
    }
  }
}

// ------- bf16-top-64 preselect -> exact rescore -> exact top-50 -> message -------
__global__ __launch_bounds__(256) void msg_kernel(
    const int* __restrict__ counters, const int* __restrict__ cand_idx,
    const float* __restrict__ cand_score, const float* __restrict__ memf,
    float* __restrict__ pc, const int* __restrict__ active)
{
  if (*active == 0) return;
  __shared__ float sc[CAP]; __shared__ int si[CAP];
  __shared__ __align__(16) float gl[DIM];
  __shared__ int pi_[PRESEL]; __shared__ float exv[PRESEL];
  __shared__ float selv[50]; __shared__ int seli[50]; __shared__ float attn[50];
  __shared__ float wv[4]; __shared__ int wi[4];
  __shared__ float bc;
  int p = blockIdx.x, t = threadIdx.x;
  int n = counters[p]; if (n > CAP) n = CAP;
  #pragma unroll
  for (int j = 0; j < 3; ++j) gl[t + j*256] = pc[(size_t)p*DIM + t + j*256];
  for (int i = t; i < CAP; i += 256){
    sc[i] = (i < n) ? cand_score[(size_t)p*CAP + i] : -3e38f;
    si[i] = (i < n) ? cand_idx[(size_t)p*CAP + i] : 0;
  }
  if (t < PRESEL) exv[t] = -3e38f;
  __syncthreads();
  // phase 1: top-PRESEL by stored MFMA score
  int NS = n < PRESEL ? n : PRESEL;
  for (int r = 0; r < NS; ++r){
    float v = -3e38f; int idx = 0;
    #pragma unroll
    for (int j = 0; j < 4; ++j){
      int ii = t*4 + j; float x = sc[ii];
      if (x > v){ v = x; idx = ii; }
    }
    for (int off = 32; off > 0; off >>= 1){
      float ov = __shfl_down(v, off, 64); int oi = __shfl_down(idx, off, 64);
      if (ov > v || (ov == v && oi < idx)){ v = ov; idx = oi; }
    }
    if ((t & 63) == 0){ wv[t >> 6] = v; wi[t >> 6] = idx; }
    __syncthreads();
    if (t == 0){
      float bv = wv[0]; int bi = wi[0];
      for (int q = 1; q < 4; ++q)
        if (wv[q] > bv || (wv[q] == bv && wi[q] < bi)){ bv = wv[q]; bi = wi[q]; }
      pi_[r] = si[bi]; sc[bi] = -3e38f;
    }
    __syncthreads();
  }
  // phase 2: exact f32 rescore of the preselected
  int w = t >> 6, lane = t & 63;
  for (int i = w; i < NS; i += 4){
    const float* row = memf + (size_t)pi_[i]*DIM;
    float s = 0.f;
    #pragma unroll
    for (int j = 0; j < 12; ++j){
      int d = lane + j*64;
      s += row[d] * gl[d];
    }
    for (int off = 32; off > 0; off >>= 1) s += __shfl_down(s, off, 64);
    if (lane == 0) exv[i] = s;
  }
  __syncthreads();
  // phase 3: exact top-50 among PRESEL
  int K = NS < 50 ? NS : 50;
  for (int r = 0; r < K; ++r){
    float v = (t < PRESEL) ? exv[t] : -3e38f; int idx = (t < PRESEL) ? t : 0;
    for (int off = 32; off > 0; off >>= 1){
      float ov = __shfl_down(v, off, 64); int oi = __shfl_down(idx, off, 64);
      if (ov > v || (ov == v && oi < idx)){ v = ov; idx = oi; }
    }
    if ((t & 63) == 0){ wv[t >> 6] = v; wi[t >> 6] = idx; }
    __syncthreads();
    if (t == 0){
      float bv = wv[0]; int bi = wi[0];
      for (int q = 1; q < 4; ++q)
        if (wv[q] > bv || (wv[q] == bv && wi[q] < bi)){ bv = wv[q]; bi = wi[q]; }
      selv[r] = bv; seli[r] = pi_[bi]; exv[bi] = -3e38f;
    }
    __syncthreads();
  }
  if (t < K) attn[t] = __expf((selv[t] - selv[0]) * TAUINV);
  __syncthreads();
  if (t == 0){ float s = 0.f; for (int k = 0; k < K; ++k) s += attn[k]; bc = s; }
  __syncthreads();
  float inv = 1.0f / bc;
  int d0 = t, d1 = t + 256, d2 = t + 512;
  float a0 = gl[d0], a1 = gl[d1], a2 = gl[d2];
  for (int k = 0; k < K; ++k){
    float a = attn[k] * inv;
    const float* row = memf + (size_t)seli[k]*DIM;
    a0 += a * row[d0]; a1 += a * row[d1]; a2 += a * row[d2];
  }
  float ss = a0*a0 + a1*a1 + a2*a2;
  for (int off = 32; off > 0; off >>= 1) ss += __shfl_down(ss, off, 64);
  if ((t & 63) == 0) wv[t >> 6] = ss;
  __syncthreads();
  if (t == 0) bc = wv[0] + wv[1] + wv[2] + wv[3];
  __syncthreads();
  float rn = 1.0f / fmaxf(sqrtf(bc), 1e-12f);
  float* orow = pc + (size_t)p*DIM;
  orow[d0] = a0 * rn; orow[d1] = a1 * rn; orow[d2] = a2 * rn;
}

// ---------------- evidence softmax stats ----------------
__global__ __launch_bounds__(256) void pl1_kernel(
    const unsigned* __restrict__ ev_key, float* __restrict__ stats, const int* __restrict__ active)
{
  if (*active == 0) return;
  __shared__ float wv[4]; __shared__ float bc;
  int t = threadIdx.x;
  float m = -3e38f;
  for (int i = t; i < NPATCH; i += 256) m = fmaxf(m, decf(ev_key[i]));
  for (int off = 32; off > 0; off >>= 1) m = fmaxf(m, __shfl_down(m, off, 64));
  if ((t & 63) == 0) wv[t >> 6] = m;
  __syncthreads();
  if (t == 0) bc = fmaxf(fmaxf(wv[0], wv[1]), fmaxf(wv[2], wv[3]));
  __syncthreads();
  float M = bc;
  __syncthreads();
  float s = 0.f;
  for (int i = t; i < NPATCH; i += 256) s += __expf((decf(ev_key[i]) - M) * TAUINV);
  for (int off = 32; off > 0; off >>= 1) s += __shfl_down(s, off, 64);
  if ((t & 63) == 0) wv[t >> 6] = s;
  __syncthreads();
  if (t == 0){ stats[0] = M; stats[1] = wv[0] + wv[1] + wv[2] + wv[3]; }
}

// ---------------- weighted pooling partials ----------------
__global__ __launch_bounds__(256) void pl2_kernel(
    const unsigned* __restrict__ ev_key, const float* __restrict__ stats,
    const float* __restrict__ pc, float* __restrict__ g_part, const int* __restrict__ active)
{
  if (*active == 0) return;
  int t = threadIdx.x, pbase = blockIdx.x * 64;
  float M = stats[0], invS = 1.0f / stats[1];
  float a0 = 0.f, a1 = 0.f, a2 = 0.f;
  for (int i = 0; i < 64; ++i){
    int p = pbase + i;
    float wgt = __expf((decf(ev_key[p]) - M) * TAUINV) * invS;
    const float* row = pc + (size_t)p*DIM;
    a0 += wgt * row[t]; a1 += wgt * row[t + 256]; a2 += wgt * row[t + 512];
  }
  g_part[blockIdx.x*DIM + t]       = a0;
  g_part[blockIdx.x*DIM + t + 256] = a1;
  g_part[blockIdx.x*DIM + t + 512] = a2;
}

// ------- logits + entropy + commit (INIT: g=tg; else reduce g_part + norm) -------
template<bool INIT>
__global__ __launch_bounds__(256) void cm_kernel(
    const float* __restrict__ gsrc, const float* __restrict__ protos,
    float* __restrict__ logits_cur, int* __restrict__ step, int* __restrict__ active)
{
  if (!INIT && *active == 0) return;
  __shared__ __align__(16) float gl[DIM];
  __shared__ float lg[NCLS];
  __shared__ float wv[4]; __shared__ float bc;
  int t = threadIdx.x;
  if (INIT){
    #pragma unroll
    for (int j = 0; j < 3; ++j) gl[t + j*256] = gsrc[t + j*256];
  } else {
    float gv[3]; float ss = 0.f;
    #pragma unroll
    for (int j = 0; j < 3; ++j){
      int d = t + j*256;
      float s = 0.f;
      for (int b2 = 0; b2 < 32; ++b2) s += gsrc[b2*DIM + d];
      gv[j] = s; ss += s*s;
    }
    for (int off = 32; off > 0; off >>= 1) ss += __shfl_down(ss, off, 64);
    if ((t & 63) == 0) wv[t >> 6] = ss;
    __syncthreads();
    if (t == 0) bc = wv[0] + wv[1] + wv[2] + wv[3];
    __syncthreads();
    float rn = 1.0f / fmaxf(sqrtf(bc), 1e-12f);
    #pragma unroll
    for (int j = 0; j < 3; ++j) gl[t + j*256] = gv[j] * rn;
  }
  __syncthreads();
  for (int c = t; c < NCLS; c += 256){
    const float4* pr = (const float4*)(protos + (size_t)c*DIM);
    float s = 0.f;
    #pragma unroll 4
    for (int d4 = 0; d4 < DIM/4; ++d4){
      float4 pv = pr[d4];
      float4 gv = *(const float4*)&gl[d4*4];
      s += gv.x*pv.x + gv.y*pv.y + gv.z*pv.z + gv.w*pv.w;
    }
    float L = 100.0f * s;
    lg[c] = L; logits_cur[c] = L;
  }
  __syncthreads();
  float m = -3e38f;
  for (int c = t; c < NCLS; c += 256) m = fmaxf(m, lg[c]);
  for (int off = 32; off > 0; off >>= 1) m = fmaxf(m, __shfl_down(m, off, 64));
  if ((t & 63) == 0) wv[t >> 6] = m;
  __syncthreads();
  if (t == 0) bc = fmaxf(fmaxf(wv[0], wv[1]), fmaxf(wv[2], wv[3]));
  __syncthreads();
  float M = bc;
  __syncthreads();
  float s = 0.f;
  for (int c = t; c < NCLS; c += 256) s += __expf(lg[c] - M);
  for (int off = 32; off > 0; off >>= 1) s += __shfl_down(s, off, 64);
  if ((t & 63) == 0) wv[t >> 6] = s;
  __syncthreads();
  if (t == 0) bc = wv[0] + wv[1] + wv[2] + wv[3];
  __syncthreads();
  float S = bc;
  __syncthreads();
  float hp = 0.f;
  for (int c = t; c < NCLS; c += 256){
    float pcl = __expf(lg[c] - M) / S;
    hp += pcl * __logf(pcl + 1e-10f);
  }
  for (int off = 32; off > 0; off >>= 1) hp += __shfl_down(hp, off, 64);
  if ((t & 63) == 0) wv[t >> 6] = hp;
  __syncthreads();
  if (t == 0){
    float H = -(wv[0] + wv[1] + wv[2] + wv[3]);
    if (INIT){ *step = 0; *active = (H > 0.8f) ? 1 : 0; }
    else     { *step = *step + 1; *active = (H > 0.8f) ? 1 : 0; }
  }
}

// ---------------- publish ----------------
__global__ void pub_kernel(const float* __restrict__ logits_cur, const int* __restrict__ step,
                           float* __restrict__ out)
{
  int i = blockIdx.x*256 + threadIdx.x;
  if (i < NCLS) out[i] = logits_cur[i];
  else if (i == NCLS) out[i] = (float)(*step);
}

extern "C" void kernel_launch(void* const* d_in, const int* in_sizes, int n_in,
                              void* d_out, int out_size, void* d_ws, size_t ws_size,
                              hipStream_t stream)
{
  (void)in_sizes; (void)n_in; (void)out_size; (void)ws_size;
  const float* tg  = (const float*)d_in[0];   // [1,768]
  const float* tp  = (const float*)d_in[1];   // [2048,768]
  const float* mem = (const float*)d_in[2];   // [65536,768]
  const float* anc = (const float*)d_in[3];   // [1000,768]
  const float* cs  = (const float*)d_in[4];   // [1000,768]
  const float* cc  = (const float*)d_in[5];   // [1000]

  char* ws = (char*)d_ws;
  auto al = [](size_t x){ return (x + 255) & ~(size_t)255; };
  size_t OFF_PC   = 0;
  size_t OFF_PROT = al(OFF_PC   + (size_t)NPATCH*DIM*4);
  size_t OFF_ABF  = al(OFF_PROT + (size_t)NCLS*DIM*4);
  size_t OFF_MBF  = al(OFF_ABF  + (size_t)1024*DIM*2);
  size_t OFF_SLAB = al(OFF_MBF  + (size_t)NMEM*DIM*2);
  size_t OFF_SS   = al(OFF_SLAB + (size_t)NPATCH*DIM*2);
  size_t OFF_THR  = al(OFF_SS   + (size_t)NPATCH*NSAMP*4);
  size_t OFF_CNT  = al(OFF_THR  + (size_t)NPATCH*4);
  size_t OFF_CI   = al(OFF_CNT  + (size_t)NPATCH*4);
  size_t OFF_CSC  = al(OFF_CI   + (size_t)NPATCH*CAP*4);
  size_t OFF_EV   = al(OFF_CSC  + (size_t)NPATCH*CAP*4);
  size_t OFF_STAT = al(OFF_EV   + (size_t)NPATCH*4);
  size_t OFF_GP   = al(OFF_STAT + 256);
  size_t OFF_LC   = al(OFF_GP   + (size_t)32*DIM*4);
  size_t OFF_STEP = al(OFF_LC   + (size_t)NCLS*4);

  float*          pc      = (float*)(ws + OFF_PC);
  float*          protos  = (float*)(ws + OFF_PROT);
  unsigned short* abf     = (unsigned short*)(ws + OFF_ABF);
  unsigned short* mbf     = (unsigned short*)(ws + OFF_MBF);
  unsigned short* slab    = (unsigned short*)(ws + OFF_SLAB);
  float*          simss   = (float*)(ws + OFF_SS);
  float*          thr     = (float*)(ws + OFF_THR);
  int*            cnt     = (int*)(ws + OFF_CNT);
  int*            ci      = (int*)(ws + OFF_CI);
  float*          csc     = (float*)(ws + OFF_CSC);
  unsigned*       evk     = (unsigned*)(ws + OFF_EV);
  float*          stats   = (float*)(ws + OFF_STAT);
  float*          gp      = (float*)(ws + OFF_GP);
  float*          lc      = (float*)(ws + OFF_LC);
  int*            stepp   = (int*)(ws + OFF_STEP);
  int*            activep = stepp + 1;

  proto_kernel<<<1024, 256, 0, stream>>>(anc, cs, cc, protos, abf);
  prep_patches<<<(NPATCH*DIM/4)/256, 256, 0, stream>>>(tp, pc);
  conv_kernel<<<(NMEM*12)/256, 256, 0, stream>>>(mem, mbf);
  cm_kernel<true><<<1, 256, 0, stream>>>(tg, protos, lc, stepp, activep);
  slab_kernel<<<NPATCH/2, 192, 0, stream>>>(pc, slab, nullptr);

  for (int it = 0; it < 3; ++it){
    zero_kernel<<<NPATCH/256, 256, 0, stream>>>(cnt, evk, activep);
    gemm_kernel<1><<<(NSAMP/128)*16, 256, 0, stream>>>(mbf, 0, slab, thr, cnt, ci, csc, simss, evk, activep);
    thresh_kernel<<<NPATCH, 256, 0, stream>>>(simss, thr, cnt, ci, csc, activep);
    gemm_kernel<0><<<((NMEM-NSAMP)/128)*16, 256, 0, stream>>>(mbf, NSAMP, slab, thr, cnt, ci, csc, simss, evk, activep);
    msg_kernel<<<NPATCH, 256, 0, stream>>>(cnt, ci, csc, mem, pc, activep);
    slab_kernel<<<NPATCH/2, 192, 0, stream>>>(pc, slab, activep);
    gemm_kernel<2><<<(1024/128)*16, 256, 0, stream>>>(abf, 0, slab, thr, cnt, ci, csc, simss, evk, activep);
    pl1_kernel<<<1, 256, 0, stream>>>(evk, stats, activep);
    pl2_kernel<<<32, 256, 0, stream>>>(evk, stats, pc, gp, activep);
    cm_kernel<false><<<1, 256, 0, stream>>>(gp, protos, lc, stepp, activep);
  }
  pub_kernel<<<4, 256, 0, stream>>>(lc, stepp, (float*)d_out);
}